// Round 9
// baseline (54.721 us; speedup 1.0000x reference)
//
#include <hip/hip_runtime.h>
#include <hip/hip_bf16.h>

typedef unsigned short u16;
typedef __attribute__((ext_vector_type(8))) short short8;   // 8 bf16 = 4 VGPR
typedef __attribute__((ext_vector_type(4))) float f32x4;

#define MAXC 256

__device__ __forceinline__ float b2f(u16 b) {
    return __uint_as_float(((unsigned)b) << 16);
}
// fp32 -> bf16 RNE
__device__ __forceinline__ u16 f2b(float f) {
    unsigned u = __float_as_uint(f);
    return (u16)((u + 0x7FFFu + ((u >> 16) & 1u)) >> 16);
}
__device__ __forceinline__ short8 load_cvt8(const float* __restrict__ p) {
    float4 f0 = *(const float4*)p;
    float4 f1 = *(const float4*)(p + 4);
    short8 r;
    r[0] = (short)f2b(f0.x); r[1] = (short)f2b(f0.y);
    r[2] = (short)f2b(f0.z); r[3] = (short)f2b(f0.w);
    r[4] = (short)f2b(f1.x); r[5] = (short)f2b(f1.y);
    r[6] = (short)f2b(f1.z); r[7] = (short)f2b(f1.w);
    return r;
}

// ---------------------------------------------------------------------------
// K1 prep, 3 roles: [0,192) clear 2MB mask; [192,256) detect int64 layout
// (per-block ORs of odd int32 words -> orbuf, all-zero <=> int64);
// [256,384) convert Wp fp32 -> bf16.
// ---------------------------------------------------------------------------
__global__ __launch_bounds__(256) void prep_kernel(
    const int* __restrict__ e, int E,
    uint4* __restrict__ maskv, int mask16,
    unsigned* __restrict__ orbuf,
    const float* __restrict__ Wp, u16* __restrict__ wpb)
{
    int b = blockIdx.x, t = threadIdx.x;
    if (b < 192) {
        uint4 z = {0u, 0u, 0u, 0u};
        for (int i = b * 256 + t; i < mask16; i += 192 * 256) maskv[i] = z;
    } else if (b < 256) {
        int bb = b - 192;
        unsigned acc = 0;
        for (int i = bb * 256 + t; i < E; i += 64 * 256)
            acc |= (unsigned)e[2 * i + 1];
        __shared__ unsigned red[4];
        #pragma unroll
        for (int o = 32; o > 0; o >>= 1) acc |= __shfl_xor(acc, o, 64);
        if ((t & 63) == 0) red[t >> 6] = acc;
        __syncthreads();
        if (t == 0) orbuf[bb] = red[0] | red[1] | red[2] | red[3];
    } else {
        int i = (b - 256) * 256 + t;          // 0..32767 float4 slots (128K floats)
        float4 f = ((const float4*)Wp)[i];
        u16* d = wpb + 4 * (size_t)i;
        d[0] = f2b(f.x); d[1] = f2b(f.y); d[2] = f2b(f.z); d[3] = f2b(f.w);
    }
}

// ---------------------------------------------------------------------------
// K2 fused: blocks [0,128) scatter edges into the bitmask (atomicOr dedups,
// idempotent -> deterministic); blocks [128,512) QKV MFMA GEMM with
// on-the-fly fp32->bf16 conversion (W tile staged bf16 in LDS).
// ---------------------------------------------------------------------------
__global__ __launch_bounds__(256) void scatter_qkv_kernel(
    const int* __restrict__ e, int E, int N,
    unsigned* __restrict__ mask, const unsigned* __restrict__ orbuf,
    const float* __restrict__ x,
    const float* __restrict__ Wq, const float* __restrict__ Wk,
    const float* __restrict__ Wv,
    const float* __restrict__ bq, const float* __restrict__ bk,
    const float* __restrict__ bv,
    u16* __restrict__ q, u16* __restrict__ k, u16* __restrict__ v)
{
    __shared__ u16 Wl[64][264];
    int t = threadIdx.x;

    if (blockIdx.x < 128) {
        unsigned oo = orbuf[t & 63];
        #pragma unroll
        for (int o = 32; o > 0; o >>= 1) oo |= __shfl_xor(oo, o, 64);
        bool i32mode = (oo != 0);
        int nw = N >> 5;
        for (int i = blockIdx.x * 256 + t; i < E; i += 128 * 256) {
            int row, col;
            if (i32mode) { row = e[i];     col = e[E + i]; }
            else         { row = e[2 * i]; col = e[2 * E + 2 * i]; }
            if ((unsigned)row < (unsigned)N && (unsigned)col < (unsigned)N)
                atomicOr(&mask[(size_t)row * nw + (col >> 5)], 1u << (col & 31));
        }
        return;
    }

    int bid = blockIdx.x - 128;                // 0..383
    int bx = bid & 31, by = bid >> 5;          // 32 row tiles x 12 col tiles
    int which = by >> 2;                       // 0=q 1=k 2=v
    int ncl = (by & 3) * 64;
    const float* Ws   = (which == 0) ? Wq : (which == 1) ? Wk : Wv;
    const float* bias = (which == 0) ? bq : (which == 1) ? bk : bv;
    u16*         T    = (which == 0) ? q  : (which == 1) ? k  : v;

    for (int s = t; s < 4096; s += 256) {
        int r  = s >> 6;
        int c4 = (s & 63) << 2;
        float4 f = *(const float4*)&Ws[(size_t)(ncl + r) * 256 + c4];
        Wl[r][c4 + 0] = f2b(f.x); Wl[r][c4 + 1] = f2b(f.y);
        Wl[r][c4 + 2] = f2b(f.z); Wl[r][c4 + 3] = f2b(f.w);
    }
    __syncthreads();

    int wv = t >> 6, l = t & 63, lr = l & 15, lk = l >> 4;
    int m0 = bx * 128 + wv * 32;
    f32x4 acc[2][4] = {};
    const float* a0b = x + (size_t)(m0 + lr) * 256 + lk * 8;
    const float* a1b = a0b + 16 * 256;

    #pragma unroll
    for (int kk = 0; kk < 8; kk++) {
        short8 a0 = load_cvt8(a0b + kk * 32);
        short8 a1 = load_cvt8(a1b + kk * 32);
        #pragma unroll
        for (int j = 0; j < 4; j++) {
            short8 b = *(const short8*)&Wl[j * 16 + lr][lk * 8 + kk * 32];
            acc[0][j] = __builtin_amdgcn_mfma_f32_16x16x32_bf16(a0, b, acc[0][j], 0, 0, 0);
            acc[1][j] = __builtin_amdgcn_mfma_f32_16x16x32_bf16(a1, b, acc[1][j], 0, 0, 0);
        }
    }
    #pragma unroll
    for (int i2 = 0; i2 < 2; i2++)
        #pragma unroll
        for (int j = 0; j < 4; j++)
            #pragma unroll
            for (int r = 0; r < 4; r++) {
                int grow = m0 + i2 * 16 + lk * 4 + r;
                int gc   = ncl + j * 16 + lr;
                T[(size_t)grow * 256 + gc] = f2b(acc[i2][j][r] + bias[gc]);
            }
}

// ---------------------------------------------------------------------------
// K3 attn+final fused: out rows depend only on x/y rows -> block-diagonal.
// 256 blocks x 1024 threads (16 waves). Wave wv: attn for row blk*16+wv
// (identical to R8's proven wave-per-row attn), y -> LDS (row pad +8 bf16);
// one syncthreads; then wave wv computes out tile rows [blk*16,+16) x cols
// [wv*16,+16), K=512: A = x (cvt on the fly) | y_lds, B = pre-converted Wp
// from global (L2-resident). Global y buffer eliminated entirely.
// ---------------------------------------------------------------------------
__global__ __launch_bounds__(1024) void attn_final_kernel(
    const unsigned* __restrict__ mask,
    const u16* __restrict__ qb, const u16* __restrict__ kb,
    const u16* __restrict__ vb,
    const float* __restrict__ x, const u16* __restrict__ wpb,
    const float* __restrict__ bp, float* __restrict__ out, int N)
{
    __shared__ int   cols[16][MAXC];     // 16 KB
    __shared__ float ws[16][8][16];      // 8 KB
    __shared__ float fs[16][8];
    __shared__ float lsums[16][8];
    __shared__ u16   ylds[16][264];      // 8.25 KB, +8 pad

    int t = threadIdx.x;
    int wv = t >> 6, lane = t & 63;
    int m0 = blockIdx.x * 16;
    int n = m0 + wv;
    int nw = N >> 5;                        // 128

    // ---- per-wave compaction (fixed order -> deterministic) ----
    unsigned wa = mask[(size_t)n * nw + lane];
    unsigned wb = mask[(size_t)n * nw + 64 + lane];
    int pc = __popc(wa) + __popc(wb);
    int scan = pc;
    #pragma unroll
    for (int o = 1; o < 64; o <<= 1) {
        int pv = __shfl_up(scan, o, 64);
        if (lane >= o) scan += pv;
    }
    int cnt = __shfl(scan, 63, 64);
    if (cnt > MAXC) cnt = MAXC;
    int off = scan - pc;
    while (wa && off < MAXC) {
        int b = __ffs(wa) - 1; wa &= wa - 1;
        cols[wv][off++] = (lane << 5) + b;
    }
    while (wb && off < MAXC) {
        int b = __ffs(wb) - 1; wb &= wb - 1;
        cols[wv][off++] = ((64 + lane) << 5) + b;
    }
    asm volatile("s_waitcnt lgkmcnt(0)" ::: "memory");

    int h8 = lane >> 4;                 // head pair (h8, h8+4)
    int jl = lane & 15;                 // neighbor slot in chunk
    int hv = lane >> 3;                 // V-phase head
    int d0 = lane * 4;                  // V-phase dims d0..d0+3

    const short8* qpA = (const short8*)(qb + (size_t)n * 256 + h8 * 32);
    const short8* qpB = (const short8*)(qb + (size_t)n * 256 + (h8 + 4) * 32);
    short8 qA0 = qpA[0], qA1 = qpA[1];
    short8 qB0 = qpB[0], qB1 = qpB[1];

    const float scale = 0.17677669529663687f;   // 1/sqrt(32)
    float mxA = -1e30f, mxB = -1e30f, lsA = 0.f, lsB = 0.f;
    float acc0 = 0.f, acc1 = 0.f, acc2 = 0.f, acc3 = 0.f;

    for (int c0 = 0; c0 < cnt; c0 += 16) {
        int cc = min(16, cnt - c0);
        float s0 = -1e30f, s1 = -1e30f;
        if (jl < cc) {
            const u16* kr = kb + (size_t)cols[wv][c0 + jl] * 256;
            short8 a0 = ((const short8*)(kr + h8 * 32))[0];
            short8 a1 = ((const short8*)(kr + h8 * 32))[1];
            short8 b0 = ((const short8*)(kr + (h8 + 4) * 32))[0];
            short8 b1 = ((const short8*)(kr + (h8 + 4) * 32))[1];
            float sa = 0.f, sb = 0.f;
            #pragma unroll
            for (int e2 = 0; e2 < 8; e2++) {
                sa = fmaf(b2f((u16)a0[e2]), b2f((u16)qA0[e2]), sa);
                sa = fmaf(b2f((u16)a1[e2]), b2f((u16)qA1[e2]), sa);
                sb = fmaf(b2f((u16)b0[e2]), b2f((u16)qB0[e2]), sb);
                sb = fmaf(b2f((u16)b1[e2]), b2f((u16)qB1[e2]), sb);
            }
            s0 = sa * scale; s1 = sb * scale;
        }
        float cm0 = s0, cm1 = s1;
        #pragma unroll
        for (int o = 8; o > 0; o >>= 1) {
            cm0 = fmaxf(cm0, __shfl_xor(cm0, o, 16));
            cm1 = fmaxf(cm1, __shfl_xor(cm1, o, 16));
        }
        float mnA = fmaxf(mxA, cm0), mnB = fmaxf(mxB, cm1);
        float fA = __expf(mxA - mnA), fB = __expf(mxB - mnB);
        float w0 = (jl < cc) ? __expf(s0 - mnA) : 0.f;
        float w1 = (jl < cc) ? __expf(s1 - mnB) : 0.f;
        float t0 = w0, t1 = w1;
        #pragma unroll
        for (int o = 8; o > 0; o >>= 1) {
            t0 += __shfl_xor(t0, o, 16);
            t1 += __shfl_xor(t1, o, 16);
        }
        lsA = lsA * fA + t0;  lsB = lsB * fB + t1;
        mxA = mnA;            mxB = mnB;

        ws[wv][h8][jl]     = w0;
        ws[wv][h8 + 4][jl] = w1;
        if (jl == 0) { fs[wv][h8] = fA; fs[wv][h8 + 4] = fB; }
        asm volatile("s_waitcnt lgkmcnt(0)" ::: "memory");

        float fv = fs[wv][hv];
        acc0 *= fv; acc1 *= fv; acc2 *= fv; acc3 *= fv;
        for (int j = 0; j < cc; j++) {
            float wj = ws[wv][hv][j];
            uint2 raw = *(const uint2*)(vb + (size_t)cols[wv][c0 + j] * 256 + d0);
            acc0 = fmaf(wj, b2f((u16)(raw.x & 0xffff)), acc0);
            acc1 = fmaf(wj, b2f((u16)(raw.x >> 16)),    acc1);
            acc2 = fmaf(wj, b2f((u16)(raw.y & 0xffff)), acc2);
            acc3 = fmaf(wj, b2f((u16)(raw.y >> 16)),    acc3);
        }
    }

    if (jl == 0) { lsums[wv][h8] = lsA; lsums[wv][h8 + 4] = lsB; }
    asm volatile("s_waitcnt lgkmcnt(0)" ::: "memory");
    float lsv = lsums[wv][hv];
    uint2 ov;
    if (cnt > 0) {
        ov.x = (unsigned)f2b(acc0 / lsv) | ((unsigned)f2b(acc1 / lsv) << 16);
        ov.y = (unsigned)f2b(acc2 / lsv) | ((unsigned)f2b(acc3 / lsv) << 16);
    } else {
        ov.x = 0u; ov.y = 0u;
    }
    *(uint2*)&ylds[wv][d0] = ov;
    __syncthreads();

    // ---- final GEMM phase: wave wv -> out rows [m0,m0+16) x cols [wv*16,+16)
    {
        int lr = lane & 15, lk = lane >> 4;
        int n0 = wv * 16;
        f32x4 facc = {};
        const float* axb = x + (size_t)(m0 + lr) * 256 + lk * 8;
        const short8* wp_ = (const short8*)(wpb + (size_t)(n0 + lr) * 512 + lk * 8);

        #pragma unroll
        for (int kk = 0; kk < 16; kk++) {
            short8 a;
            if (kk < 8) a = load_cvt8(axb + kk * 32);
            else        a = *(const short8*)&ylds[lr][(kk - 8) * 32 + lk * 8];
            short8 b = wp_[kk * 4];   // +32 bf16 along K per step
            facc = __builtin_amdgcn_mfma_f32_16x16x32_bf16(a, b, facc, 0, 0, 0);
        }
        #pragma unroll
        for (int r = 0; r < 4; r++) {
            int grow = m0 + lk * 4 + r;
            int gc   = n0 + lr;
            out[(size_t)grow * 256 + gc] = facc[r] + bp[gc];
        }
    }
}

// ---------------------------------------------------------------------------
extern "C" void kernel_launch(void* const* d_in, const int* in_sizes, int n_in,
                              void* d_out, int out_size, void* d_ws, size_t ws_size,
                              hipStream_t stream) {
    const float* x  = (const float*)d_in[0];
    const int*   ei = (const int*)d_in[1];
    const float* Wq = (const float*)d_in[2];
    const float* bq = (const float*)d_in[3];
    const float* Wk = (const float*)d_in[4];
    const float* bk = (const float*)d_in[5];
    const float* Wv = (const float*)d_in[6];
    const float* bv = (const float*)d_in[7];
    const float* Wp = (const float*)d_in[8];
    const float* bp = (const float*)d_in[9];
    float* out = (float*)d_out;

    const int D = 256;
    int N = in_sizes[0] / D;       // 4096
    int E = in_sizes[1] / 2;       // 135168

    size_t maskB = (size_t)N * (N >> 5) * sizeof(unsigned);   // 2 MB
    char* ws = (char*)d_ws;
    unsigned* mask  = (unsigned*)ws;
    unsigned* orbuf = (unsigned*)(ws + maskB);                // 64 words
    u16* qbb = (u16*)(ws + maskB + 512);
    u16* kbb = qbb + (size_t)N * D;
    u16* vbb = kbb + (size_t)N * D;
    u16* wpb = vbb + (size_t)N * D;                           // 131072 bf16

    prep_kernel<<<384, 256, 0, stream>>>(ei, E, (uint4*)ws, (int)(maskB / 16),
                                         orbuf, Wp, wpb);

    scatter_qkv_kernel<<<512, 256, 0, stream>>>(
        ei, E, N, mask, orbuf, x, Wq, Wk, Wv, bq, bk, bv, qbb, kbb, vbb);

    attn_final_kernel<<<N / 16, 1024, 0, stream>>>(
        mask, qbb, kbb, vbb, x, wpb, bp, out, N);
}

// Round 10
// 51.632 us; speedup vs baseline: 1.0598x; 1.0598x over previous
//
#include <hip/hip_runtime.h>
#include <hip/hip_bf16.h>

typedef unsigned short u16;
typedef __attribute__((ext_vector_type(8))) short short8;   // 8 bf16 = 4 VGPR
typedef __attribute__((ext_vector_type(4))) float f32x4;

#define MAXC 256

__device__ __forceinline__ float b2f(u16 b) {
    return __uint_as_float(((unsigned)b) << 16);
}
// fp32 -> bf16 RNE
__device__ __forceinline__ u16 f2b(float f) {
    unsigned u = __float_as_uint(f);
    return (u16)((u + 0x7FFFu + ((u >> 16) & 1u)) >> 16);
}
__device__ __forceinline__ short8 load_cvt8(const float* __restrict__ p) {
    float4 f0 = *(const float4*)p;
    float4 f1 = *(const float4*)(p + 4);
    short8 r;
    r[0] = (short)f2b(f0.x); r[1] = (short)f2b(f0.y);
    r[2] = (short)f2b(f0.z); r[3] = (short)f2b(f0.w);
    r[4] = (short)f2b(f1.x); r[5] = (short)f2b(f1.y);
    r[6] = (short)f2b(f1.z); r[7] = (short)f2b(f1.w);
    return r;
}

// ---------------------------------------------------------------------------
// K1 prep, 3 roles: [0,192) clear 2MB mask; [192,256) detect int64 layout
// (per-block ORs of odd int32 words -> orbuf, all-zero <=> int64);
// [256,384) convert Wp fp32 -> bf16.
// ---------------------------------------------------------------------------
__global__ __launch_bounds__(256) void prep_kernel(
    const int* __restrict__ e, int E,
    uint4* __restrict__ maskv, int mask16,
    unsigned* __restrict__ orbuf,
    const float* __restrict__ Wp, u16* __restrict__ wpb)
{
    int b = blockIdx.x, t = threadIdx.x;
    if (b < 192) {
        uint4 z = {0u, 0u, 0u, 0u};
        for (int i = b * 256 + t; i < mask16; i += 192 * 256) maskv[i] = z;
    } else if (b < 256) {
        int bb = b - 192;
        unsigned acc = 0;
        for (int i = bb * 256 + t; i < E; i += 64 * 256)
            acc |= (unsigned)e[2 * i + 1];
        __shared__ unsigned red[4];
        #pragma unroll
        for (int o = 32; o > 0; o >>= 1) acc |= __shfl_xor(acc, o, 64);
        if ((t & 63) == 0) red[t >> 6] = acc;
        __syncthreads();
        if (t == 0) orbuf[bb] = red[0] | red[1] | red[2] | red[3];
    } else {
        int i = (b - 256) * 256 + t;          // 0..32767 float4 slots (128K floats)
        float4 f = ((const float4*)Wp)[i];
        u16* d = wpb + 4 * (size_t)i;
        d[0] = f2b(f.x); d[1] = f2b(f.y); d[2] = f2b(f.z); d[3] = f2b(f.w);
    }
}

// ---------------------------------------------------------------------------
// K2 fused: blocks [0,128) scatter edges into the bitmask (atomicOr dedups,
// idempotent -> deterministic); blocks [128,512) QKV MFMA GEMM with
// on-the-fly fp32->bf16 conversion (W tile staged bf16 in LDS).
// ---------------------------------------------------------------------------
__global__ __launch_bounds__(256) void scatter_qkv_kernel(
    const int* __restrict__ e, int E, int N,
    unsigned* __restrict__ mask, const unsigned* __restrict__ orbuf,
    const float* __restrict__ x,
    const float* __restrict__ Wq, const float* __restrict__ Wk,
    const float* __restrict__ Wv,
    const float* __restrict__ bq, const float* __restrict__ bk,
    const float* __restrict__ bv,
    u16* __restrict__ q, u16* __restrict__ k, u16* __restrict__ v)
{
    __shared__ u16 Wl[64][264];
    int t = threadIdx.x;

    if (blockIdx.x < 128) {
        unsigned oo = orbuf[t & 63];
        #pragma unroll
        for (int o = 32; o > 0; o >>= 1) oo |= __shfl_xor(oo, o, 64);
        bool i32mode = (oo != 0);
        int nw = N >> 5;
        for (int i = blockIdx.x * 256 + t; i < E; i += 128 * 256) {
            int row, col;
            if (i32mode) { row = e[i];     col = e[E + i]; }
            else         { row = e[2 * i]; col = e[2 * E + 2 * i]; }
            if ((unsigned)row < (unsigned)N && (unsigned)col < (unsigned)N)
                atomicOr(&mask[(size_t)row * nw + (col >> 5)], 1u << (col & 31));
        }
        return;
    }

    int bid = blockIdx.x - 128;                // 0..383
    int bx = bid & 31, by = bid >> 5;          // 32 row tiles x 12 col tiles
    int which = by >> 2;                       // 0=q 1=k 2=v
    int ncl = (by & 3) * 64;
    const float* Ws   = (which == 0) ? Wq : (which == 1) ? Wk : Wv;
    const float* bias = (which == 0) ? bq : (which == 1) ? bk : bv;
    u16*         T    = (which == 0) ? q  : (which == 1) ? k  : v;

    for (int s = t; s < 4096; s += 256) {
        int r  = s >> 6;
        int c4 = (s & 63) << 2;
        float4 f = *(const float4*)&Ws[(size_t)(ncl + r) * 256 + c4];
        Wl[r][c4 + 0] = f2b(f.x); Wl[r][c4 + 1] = f2b(f.y);
        Wl[r][c4 + 2] = f2b(f.z); Wl[r][c4 + 3] = f2b(f.w);
    }
    __syncthreads();

    int wv = t >> 6, l = t & 63, lr = l & 15, lk = l >> 4;
    int m0 = bx * 128 + wv * 32;
    f32x4 acc[2][4] = {};
    const float* a0b = x + (size_t)(m0 + lr) * 256 + lk * 8;
    const float* a1b = a0b + 16 * 256;

    #pragma unroll
    for (int kk = 0; kk < 8; kk++) {
        short8 a0 = load_cvt8(a0b + kk * 32);
        short8 a1 = load_cvt8(a1b + kk * 32);
        #pragma unroll
        for (int j = 0; j < 4; j++) {
            short8 b = *(const short8*)&Wl[j * 16 + lr][lk * 8 + kk * 32];
            acc[0][j] = __builtin_amdgcn_mfma_f32_16x16x32_bf16(a0, b, acc[0][j], 0, 0, 0);
            acc[1][j] = __builtin_amdgcn_mfma_f32_16x16x32_bf16(a1, b, acc[1][j], 0, 0, 0);
        }
    }
    #pragma unroll
    for (int i2 = 0; i2 < 2; i2++)
        #pragma unroll
        for (int j = 0; j < 4; j++)
            #pragma unroll
            for (int r = 0; r < 4; r++) {
                int grow = m0 + i2 * 16 + lk * 4 + r;
                int gc   = ncl + j * 16 + lr;
                T[(size_t)grow * 256 + gc] = f2b(acc[i2][j][r] + bias[gc]);
            }
}

// ---------------------------------------------------------------------------
// K3 attn: one row per wave (R8 structure). NEW vs R8: cols[] padded to a
// multiple of 16 with row n (self; valid address, weight exactly 0), so the
// score loads are UNCONDITIONAL and the V loop has a COMPILE-TIME bound of
// 16 -> full unroll: 16 cols LDS reads issue back-to-back, 16 V-row global
// loads in flight together, ONE memory latency per chunk instead of 16
// (R8's runtime-bounded loop serialized LDS->VMEM->fma per neighbor).
// Numerics bit-identical to R8 (padded slots: w=0, s=-1e30).
// ---------------------------------------------------------------------------
__global__ __launch_bounds__(256) void attn_kernel(
    const unsigned* __restrict__ mask,
    const u16* __restrict__ qb, const u16* __restrict__ kb,
    const u16* __restrict__ vb, u16* __restrict__ yb, int N)
{
    __shared__ int   cols[4][MAXC];
    __shared__ float ws[4][8][16];
    __shared__ float fs[4][8];
    __shared__ float lsums[4][8];

    int t = threadIdx.x;
    int wv = t >> 6, lane = t & 63;
    int n = blockIdx.x * 4 + wv;
    int nw = N >> 5;                        // 128

    // ---- per-wave compaction (fixed order -> deterministic) ----
    unsigned wa = mask[(size_t)n * nw + lane];
    unsigned wb = mask[(size_t)n * nw + 64 + lane];
    int pc = __popc(wa) + __popc(wb);
    int scan = pc;
    #pragma unroll
    for (int o = 1; o < 64; o <<= 1) {
        int pv = __shfl_up(scan, o, 64);
        if (lane >= o) scan += pv;
    }
    int cnt = __shfl(scan, 63, 64);
    if (cnt > MAXC) cnt = MAXC;
    int off = scan - pc;
    while (wa && off < MAXC) {
        int b = __ffs(wa) - 1; wa &= wa - 1;
        cols[wv][off++] = (lane << 5) + b;
    }
    while (wb && off < MAXC) {
        int b = __ffs(wb) - 1; wb &= wb - 1;
        cols[wv][off++] = ((64 + lane) << 5) + b;
    }
    // pad cols to a multiple of 16 with self-index (valid address, w == 0)
    int cntp = (cnt + 15) & ~15;
    if (cntp > MAXC) cntp = MAXC;
    for (int i = cnt + lane; i < cntp; i += 64) cols[wv][i] = n;
    asm volatile("s_waitcnt lgkmcnt(0)" ::: "memory");

    int h8 = lane >> 4;                 // head pair (h8, h8+4)
    int jl = lane & 15;                 // neighbor slot in chunk
    int hv = lane >> 3;                 // V-phase head
    int d0 = lane * 4;                  // V-phase dims d0..d0+3

    const short8* qpA = (const short8*)(qb + (size_t)n * 256 + h8 * 32);
    const short8* qpB = (const short8*)(qb + (size_t)n * 256 + (h8 + 4) * 32);
    short8 qA0 = qpA[0], qA1 = qpA[1];
    short8 qB0 = qpB[0], qB1 = qpB[1];

    const float scale = 0.17677669529663687f;   // 1/sqrt(32)
    float mxA = -1e30f, mxB = -1e30f, lsA = 0.f, lsB = 0.f;
    float acc0 = 0.f, acc1 = 0.f, acc2 = 0.f, acc3 = 0.f;

    for (int c0 = 0; c0 < cnt; c0 += 16) {
        bool valid = (c0 + jl) < cnt;
        // --- scores: unconditional loads (padded rows are valid memory) ---
        const u16* kr = kb + (size_t)cols[wv][c0 + jl] * 256;
        short8 a0 = ((const short8*)(kr + h8 * 32))[0];
        short8 a1 = ((const short8*)(kr + h8 * 32))[1];
        short8 b0 = ((const short8*)(kr + (h8 + 4) * 32))[0];
        short8 b1 = ((const short8*)(kr + (h8 + 4) * 32))[1];
        float sa = 0.f, sb = 0.f;
        #pragma unroll
        for (int e2 = 0; e2 < 8; e2++) {
            sa = fmaf(b2f((u16)a0[e2]), b2f((u16)qA0[e2]), sa);
            sa = fmaf(b2f((u16)a1[e2]), b2f((u16)qA1[e2]), sa);
            sb = fmaf(b2f((u16)b0[e2]), b2f((u16)qB0[e2]), sb);
            sb = fmaf(b2f((u16)b1[e2]), b2f((u16)qB1[e2]), sb);
        }
        float s0 = valid ? sa * scale : -1e30f;
        float s1 = valid ? sb * scale : -1e30f;

        float cm0 = s0, cm1 = s1;
        #pragma unroll
        for (int o = 8; o > 0; o >>= 1) {
            cm0 = fmaxf(cm0, __shfl_xor(cm0, o, 16));
            cm1 = fmaxf(cm1, __shfl_xor(cm1, o, 16));
        }
        float mnA = fmaxf(mxA, cm0), mnB = fmaxf(mxB, cm1);
        float fA = __expf(mxA - mnA), fB = __expf(mxB - mnB);
        float w0 = valid ? __expf(s0 - mnA) : 0.f;
        float w1 = valid ? __expf(s1 - mnB) : 0.f;
        float t0 = w0, t1 = w1;
        #pragma unroll
        for (int o = 8; o > 0; o >>= 1) {
            t0 += __shfl_xor(t0, o, 16);
            t1 += __shfl_xor(t1, o, 16);
        }
        lsA = lsA * fA + t0;  lsB = lsB * fB + t1;
        mxA = mnA;            mxB = mnB;

        ws[wv][h8][jl]     = w0;
        ws[wv][h8 + 4][jl] = w1;
        if (jl == 0) { fs[wv][h8] = fA; fs[wv][h8 + 4] = fB; }
        asm volatile("s_waitcnt lgkmcnt(0)" ::: "memory");

        // --- V accumulation: fixed 16-iteration fully-unrolled loop ---
        float fv = fs[wv][hv];
        acc0 *= fv; acc1 *= fv; acc2 *= fv; acc3 *= fv;
        #pragma unroll
        for (int j = 0; j < 16; j++) {
            float wj = ws[wv][hv][j];
            uint2 raw = *(const uint2*)(vb + (size_t)cols[wv][c0 + j] * 256 + d0);
            acc0 = fmaf(wj, b2f((u16)(raw.x & 0xffff)), acc0);
            acc1 = fmaf(wj, b2f((u16)(raw.x >> 16)),    acc1);
            acc2 = fmaf(wj, b2f((u16)(raw.y & 0xffff)), acc2);
            acc3 = fmaf(wj, b2f((u16)(raw.y >> 16)),    acc3);
        }
    }

    if (jl == 0) { lsums[wv][h8] = lsA; lsums[wv][h8 + 4] = lsB; }
    asm volatile("s_waitcnt lgkmcnt(0)" ::: "memory");
    float ls = lsums[wv][hv];
    uint2 ov;
    if (cnt > 0) {
        ov.x = (unsigned)f2b(acc0 / ls) | ((unsigned)f2b(acc1 / ls) << 16);
        ov.y = (unsigned)f2b(acc2 / ls) | ((unsigned)f2b(acc3 / ls) << 16);
    } else {
        ov.x = 0u; ov.y = 0u;
    }
    *(uint2*)(yb + (size_t)n * 256 + d0) = ov;
}

// ---------------------------------------------------------------------------
// K4 final MFMA GEMM: out = [x | y] @ Wp^T + bp, K=512, fp32 out.
// Wp pre-converted to bf16 by prep -> B-frags loaded lane-direct from
// global (L2-resident), no LDS, no syncthreads.
// ---------------------------------------------------------------------------
__global__ __launch_bounds__(256) void final_kernel(
    const float* __restrict__ x, const u16* __restrict__ yb,
    const u16* __restrict__ wpb, const float* __restrict__ bp,
    float* __restrict__ out)
{
    int t = threadIdx.x;
    int wv = t >> 6, l = t & 63, lr = l & 15, lk = l >> 4;
    int m0 = blockIdx.x * 64 + wv * 16;
    int n0 = blockIdx.y * 64;

    f32x4 acc[4] = {};
    const float* axb = x  + (size_t)(m0 + lr) * 256 + lk * 8;
    const u16*   ayb = yb + (size_t)(m0 + lr) * 256 + lk * 8;
    const short8* wp_ = (const short8*)(wpb + (size_t)(n0 + lr) * 512 + lk * 8);

    #pragma unroll
    for (int kk = 0; kk < 16; kk++) {
        short8 a;
        if (kk < 8) a = load_cvt8(axb + kk * 32);
        else        a = *(const short8*)(ayb + (kk - 8) * 32);
        #pragma unroll
        for (int j = 0; j < 4; j++) {
            short8 b = wp_[(size_t)j * 16 * 64 + kk * 4];   // +16 rows = 16*512 bf16
            acc[j] = __builtin_amdgcn_mfma_f32_16x16x32_bf16(a, b, acc[j], 0, 0, 0);
        }
    }
    #pragma unroll
    for (int j = 0; j < 4; j++)
        #pragma unroll
        for (int r = 0; r < 4; r++) {
            int grow = m0 + lk * 4 + r;
            int gc   = n0 + j * 16 + lr;
            out[(size_t)grow * 256 + gc] = acc[j][r] + bp[gc];
        }
}

// ---------------------------------------------------------------------------
extern "C" void kernel_launch(void* const* d_in, const int* in_sizes, int n_in,
                              void* d_out, int out_size, void* d_ws, size_t ws_size,
                              hipStream_t stream) {
    const float* x  = (const float*)d_in[0];
    const int*   ei = (const int*)d_in[1];
    const float* Wq = (const float*)d_in[2];
    const float* bq = (const float*)d_in[3];
    const float* Wk = (const float*)d_in[4];
    const float* bk = (const float*)d_in[5];
    const float* Wv = (const float*)d_in[6];
    const float* bv = (const float*)d_in[7];
    const float* Wp = (const float*)d_in[8];
    const float* bp = (const float*)d_in[9];
    float* out = (float*)d_out;

    const int D = 256;
    int N = in_sizes[0] / D;       // 4096
    int E = in_sizes[1] / 2;       // 135168

    size_t maskB = (size_t)N * (N >> 5) * sizeof(unsigned);   // 2 MB
    char* ws = (char*)d_ws;
    unsigned* mask  = (unsigned*)ws;
    unsigned* orbuf = (unsigned*)(ws + maskB);                // 64 words
    u16* qbb = (u16*)(ws + maskB + 512);
    u16* kbb = qbb + (size_t)N * D;
    u16* vbb = kbb + (size_t)N * D;
    u16* ybb = vbb + (size_t)N * D;
    u16* wpb = ybb + (size_t)N * D;                           // 131072 bf16

    prep_kernel<<<384, 256, 0, stream>>>(ei, E, (uint4*)ws, (int)(maskB / 16),
                                         orbuf, Wp, wpb);

    scatter_qkv_kernel<<<512, 256, 0, stream>>>(
        ei, E, N, mask, orbuf, x, Wq, Wk, Wv, bq, bk, bv, qbb, kbb, vbb);

    attn_kernel<<<N / 4, 256, 0, stream>>>(mask, qbb, kbb, vbb, ybb, N);

    dim3 gf(N / 64, 4);
    final_kernel<<<gf, 256, 0, stream>>>(x, ybb, wpb, bp, out);
}